// Round 1
// baseline (340.978 us; speedup 1.0000x reference)
//
#include <hip/hip_runtime.h>

// Problem constants (fixed by setup_inputs).
constexpr int B_   = 4;
constexpr int N_   = 16384;
constexpr int M_   = 1024;
constexpr int C_   = 64;    // feature channels
constexpr int CIN_ = 3 + C_; // 67
constexpr int COP_ = 64;    // neighbor-op out channels
constexpr int COUT_ = 128;  // final out channels
constexpr int K_   = 32;    // neighbors
constexpr float R2_ = 0.25f; // radius^2

// One wave (64 lanes) per center. Lane j owns output channel j of the
// neighbor operator (W_op column j in registers); neighbor input vectors are
// read at wave-uniform addresses (readfirstlane'd index) so the compiler can
// use scalar/broadcast loads -> inner loop is pure v_fma with SGPR operand.
__global__ __launch_bounds__(64) void pointnet_fused(
    const float* __restrict__ positions,   // (B,N,3)
    const float* __restrict__ features,    // (B,N,64)
    const float* __restrict__ centers,     // (B,M,3)
    const float* __restrict__ distances,   // (B,M,N)
    const float* __restrict__ W_op,        // (67,64)
    const float* __restrict__ b_op,        // (64)
    const float* __restrict__ W_agg,       // (64,128)
    const float* __restrict__ b_agg,       // (128)
    float* __restrict__ out)               // (B,M,128)
{
    const int j  = threadIdx.x;            // 0..63
    const int bm = blockIdx.x;             // 0..B*M-1
    const int b  = bm >> 10;               // bm / M_

    __shared__ int   s_ids[K_];
    __shared__ float s_pooled[COP_];

    // W_op column j -> registers (coalesced across lanes).
    float w[CIN_];
    #pragma unroll
    for (int c = 0; c < CIN_; ++c) w[c] = W_op[c * COP_ + j];
    const float bop_j = b_op[j];

    // Center coords (wave-uniform values).
    const float ctr0 = centers[bm * 3 + 0];
    const float ctr1 = centers[bm * 3 + 1];
    const float ctr2 = centers[bm * 3 + 2];

    // ---- Ball query: first K_ column indices with d < R2, in order ----
    const float* drow = distances + (size_t)bm * N_;
    int found = 0;
    for (int n0 = 0; n0 < N_ && found < K_; n0 += 64) {
        const float d = drow[n0 + j];
        const bool pred = d < R2_;
        const unsigned long long mask = __ballot(pred);
        const int rank = found + __popcll(mask & ((1ull << j) - 1ull));
        if (pred && rank < K_) s_ids[rank] = n0 + j;
        found += (int)__popcll(mask);
    }
    const int valid = found < K_ ? found : K_;
    __syncthreads();

    // ---- Neighbor operator + masked max-pool ----
    float pooled = -INFINITY;
    for (int k = 0; k < valid; ++k) {
        const int id = __builtin_amdgcn_readfirstlane(s_ids[k]);
        const float* pp = positions + ((size_t)b * N_ + id) * 3;
        const float* fp = features  + ((size_t)b * N_ + id) * C_;
        float acc = bop_j;
        acc = fmaf(pp[0] - ctr0, w[0], acc);
        acc = fmaf(pp[1] - ctr1, w[1], acc);
        acc = fmaf(pp[2] - ctr2, w[2], acc);
        #pragma unroll
        for (int c = 0; c < C_; ++c) acc = fmaf(fp[c], w[3 + c], acc);
        pooled = fmaxf(pooled, acc);
    }
    // Invalid slots contribute f = 0 to the max (reference index_put trick).
    if (valid < K_) pooled = fmaxf(pooled, 0.0f);

    s_pooled[j] = pooled;
    __syncthreads();

    // ---- Aggregation: out = relu(pooled @ W_agg + b_agg), 128 outs ----
    float acc0 = b_agg[j];
    float acc1 = b_agg[j + 64];
    #pragma unroll
    for (int jj = 0; jj < COP_; ++jj) {
        const float p = s_pooled[jj];           // LDS broadcast, conflict-free
        acc0 = fmaf(p, W_agg[jj * COUT_ + j],      acc0);
        acc1 = fmaf(p, W_agg[jj * COUT_ + j + 64], acc1);
    }
    float* orow = out + (size_t)bm * COUT_;
    orow[j]      = fmaxf(acc0, 0.0f);
    orow[j + 64] = fmaxf(acc1, 0.0f);
}

extern "C" void kernel_launch(void* const* d_in, const int* in_sizes, int n_in,
                              void* d_out, int out_size, void* d_ws, size_t ws_size,
                              hipStream_t stream) {
    const float* positions = (const float*)d_in[0];
    const float* features  = (const float*)d_in[1];
    const float* centers   = (const float*)d_in[2];
    const float* distances = (const float*)d_in[3];
    const float* W_op      = (const float*)d_in[4];
    const float* b_op      = (const float*)d_in[5];
    const float* W_agg     = (const float*)d_in[6];
    const float* b_agg     = (const float*)d_in[7];
    float* out = (float*)d_out;

    dim3 grid(B_ * M_);
    dim3 block(64);
    pointnet_fused<<<grid, block, 0, stream>>>(
        positions, features, centers, distances,
        W_op, b_op, W_agg, b_agg, out);
}